// Round 17
// baseline (38.248 us; speedup 1.0000x reference)
//
#include <hip/hip_runtime.h>
#include <hip/hip_fp16.h>

#define BB 16
#define DD 512
#define NN 4096
#define KK 32
#define TNS 32          // n per subtile
#define SUBT 4          // subtiles per block (block owns 128 n)
#define NGRP 32         // n-groups (blocks) per batch
#define NBLK (BB*NGRP)  // 512 blocks
#define ROWX 40         // xbuf row stride (bf16 elems), 80 B
#define ROWA 40         // a_t row stride

// LDS byte offsets (total 77824 -> 2 blocks/CU)
#define OFF_XBUF 0              // bf16 [512][40] = 40960
#define OFF_CLDS 40960          // bf16 c swizzled [32][512] = 32768
#define OFF_AT   73728          // bf16 [32][40] = 2560
#define OFF_X2P  76288          // f32 [8][32] = 1024
#define OFF_S2   77312          // f32 [32]
#define OFF_C2   77440          // f32 [32]
#define OFF_ASUM 77568          // f32 [2][32]
#define LDS_TOTAL 77824

// xbuf layout: byte(d,n) = d*80 + (((n>>3) ^ (d&3))<<4) + (n&7)*2
// (R8 anchor layout — do NOT touch; three layout excursions all regressed.)
// R15: phase B uses mfma_32x32x16 (xbuf read once/subtile).
// R16: barrier-3 removed (phase B reads only wave-own xbuf rows).
// R17: odd blocks run phase A on waves 6-7 (even: 0-1) — wave i maps to
//   SIMD i&3, so co-resident blocks' phase-A waves previously piled onto
//   SIMDs 0,1 (pairwise contention, SIMDs 2,3 idle). Spreading them across
//   all 4 SIMDs lets the two blocks' dominant phase truly overlap.

typedef unsigned short u16;
typedef __attribute__((ext_vector_type(8))) short short8v;
typedef __attribute__((ext_vector_type(4))) float f32x4;
typedef __attribute__((ext_vector_type(16))) float f32x16;

#define SYNCL() asm volatile("s_waitcnt lgkmcnt(0)\n\ts_barrier" ::: "memory")

__device__ __forceinline__ unsigned f2bf(float f) {
    union { float f; unsigned u; } v; v.f = f;
    unsigned r = v.u + 0x7fff + ((v.u >> 16) & 1);   // RNE
    return r >> 16;
}

// ---------------- K1: fused, staggered staging, folded c-prep ------------
template <typename PART>
__global__ __launch_bounds__(512, 4)
void k1_fused(const float* __restrict__ x, const float* __restrict__ cw,
              const float* __restrict__ scale,
              float* __restrict__ ws_asum, PART* __restrict__ ws_e) {
    extern __shared__ char smem[];
    u16*   xbuf    = (u16*)(smem + OFF_XBUF);
    u16*   c_lds   = (u16*)(smem + OFF_CLDS);
    u16*   a_t     = (u16*)(smem + OFF_AT);
    float* x2_part = (float*)(smem + OFF_X2P);
    float* s2_l    = (float*)(smem + OFF_S2);
    float* c2_l    = (float*)(smem + OFF_C2);
    float* asum_p  = (float*)(smem + OFF_ASUM);

    const int t = threadIdx.x;
    const int l = t & 63, w = t >> 6;        // lane, wave (8 waves)
    const int g = l >> 4, li = l & 15;       // 16-lane group, group-lane
    const int blk = blockIdx.x;
    const int b = blk >> 5, grp = blk & 31;
    const int n0 = grp * 128;
    const float* xg = x + (size_t)b * DD * NN + n0;

    // phase-A wave pair: even blocks waves 0-1 (SIMDs 0,1), odd blocks
    // waves 6-7 (SIMDs 2,3) -> co-resident blocks use disjoint SIMDs.
    const int aw = (blk & 1) ? 6 : 0;
    const bool isA = (w == aw) || (w == aw + 1);
    const int wa = w - aw;                   // 0 or 1 when isA

    // staging geometry: wave w owns rows [64w, 64w+64)
    const int lr = l >> 3;                   // row-subgroup 0..7
    const int lc = l & 7;                    // 16B fp32 col-group (4 n)
    const int cp = lc >> 1, lo = lc & 1;     // chunk + 8B half within chunk
    const float* xrow = xg + (size_t)(w * 64 + lr) * NN + lc * 4;
    // per-thread constant swizzled write offset: row r = w*64 + 8j + lr
    const int wswz = ((cp ^ (lr & 3)) << 4) | (lo << 3);

    // ---- prologue: c-row loads first ----
    const int ck = t >> 4, cseg = t & 15;    // 16 threads per k-row
    float4 cv[8];
    {
        const float* crow = cw + ck * DD + cseg * 32;
#pragma unroll
        for (int j = 0; j < 8; ++j) cv[j] = *(const float4*)(crow + 4 * j);
    }

    // ---- issue subtile-0 x loads (two halves) ----
    float4 vaA[4], vaB[4];
#pragma unroll
    for (int j = 0; j < 4; ++j) vaA[j] = *(const float4*)(xrow + (size_t)(j * 8) * NN);
#pragma unroll
    for (int j = 0; j < 4; ++j) vaB[j] = *(const float4*)(xrow + (size_t)((j + 4) * 8) * NN);

    // ---- stage c -> c_lds (chunk-swizzled) + c2 via 16-lane reduce ----
    {
        float c2p = 0.f;
#pragma unroll
        for (int j = 0; j < 8; ++j)
            c2p += cv[j].x * cv[j].x + cv[j].y * cv[j].y
                 + cv[j].z * cv[j].z + cv[j].w * cv[j].w;
#pragma unroll
        for (int j = 0; j < 4; ++j) {
            uint4 pk;
            asm("v_cvt_pk_bf16_f32 %0, %1, %2" : "=v"(pk.x) : "v"(cv[2*j].x),   "v"(cv[2*j].y));
            asm("v_cvt_pk_bf16_f32 %0, %1, %2" : "=v"(pk.y) : "v"(cv[2*j].z),   "v"(cv[2*j].w));
            asm("v_cvt_pk_bf16_f32 %0, %1, %2" : "=v"(pk.z) : "v"(cv[2*j+1].x), "v"(cv[2*j+1].y));
            asm("v_cvt_pk_bf16_f32 %0, %1, %2" : "=v"(pk.w) : "v"(cv[2*j+1].z), "v"(cv[2*j+1].w));
            const int dch = cseg * 4 + j;                 // 16B chunk idx 0..63
            *(uint4*)(smem + OFF_CLDS + ck * 1024 + ((dch ^ (ck & 7)) << 4)) = pk;
        }
        c2p += __shfl_xor(c2p, 1); c2p += __shfl_xor(c2p, 2);
        c2p += __shfl_xor(c2p, 4); c2p += __shfl_xor(c2p, 8);
        if ((l & 15) == 0) c2_l[ck] = c2p;
        if (t < KK) { float sc = scale[t]; s2_l[t] = sc * sc; }
    }

    // phase-B accumulators: 2 tiles of 32x32 (k all 32, d = w*64 + tile*32 + (l&31))
    f32x16 accW[2];
#pragma unroll
    for (int i = 0; i < 16; ++i) { accW[0][i] = 0.f; accW[1][i] = 0.f; }
    float asum_acc[8] = {0.f, 0.f, 0.f, 0.f, 0.f, 0.f, 0.f, 0.f};

#pragma unroll
    for (int s = 0; s < SUBT; ++s) {
        // ---- convert vaA/vaB -> xbuf (swizzled b64 writes) + x2 partials ----
        {
            float p0 = 0, p1 = 0, p2 = 0, p3 = 0;
#pragma unroll
            for (int j = 0; j < 8; ++j) {
                float4 v = (j < 4) ? vaA[j] : vaB[j - 4];
                uint2 pk;
                asm("v_cvt_pk_bf16_f32 %0, %1, %2" : "=v"(pk.x) : "v"(v.x), "v"(v.y));
                asm("v_cvt_pk_bf16_f32 %0, %1, %2" : "=v"(pk.y) : "v"(v.z), "v"(v.w));
                const int r = w * 64 + j * 8 + lr;
                *(uint2*)(smem + OFF_XBUF + r * 80 + wswz) = pk;
                p0 += v.x * v.x; p1 += v.y * v.y;
                p2 += v.z * v.z; p3 += v.w * v.w;
            }
            p0 += __shfl_xor(p0, 8); p0 += __shfl_xor(p0, 16); p0 += __shfl_xor(p0, 32);
            p1 += __shfl_xor(p1, 8); p1 += __shfl_xor(p1, 16); p1 += __shfl_xor(p1, 32);
            p2 += __shfl_xor(p2, 8); p2 += __shfl_xor(p2, 16); p2 += __shfl_xor(p2, 32);
            p3 += __shfl_xor(p3, 8); p3 += __shfl_xor(p3, 16); p3 += __shfl_xor(p3, 32);
            if (lr == 0) {
                float4 p4 = {p0, p1, p2, p3};
                *(float4*)((char*)smem + OFF_X2P + w * 128 + lc * 16) = p4;
            }
        }
        SYNCL();   // 1: xbuf + x2_part visible (also gates c_lds/c2/s2 at s=0;
                   //    also orders a_t(s-1) phase-B reads before softmax(s) writes)

        // ---- issue next subtile's first-half loads (all waves, early) ----
        if (s < SUBT - 1) {
#pragma unroll
            for (int j = 0; j < 4; ++j)
                vaA[j] = *(const float4*)(xrow + (size_t)(j * 8) * NN + (s + 1) * TNS);
        }

        // ---- phase A + softmax fused (2 waves, block-parity SIMD spread) ----
        if (isA) {
            __builtin_amdgcn_s_setprio(1);
            f32x4 accA0 = {0.f, 0.f, 0.f, 0.f}, accA1 = {0.f, 0.f, 0.f, 0.f};
            const int nloc = wa * 16 + li;
            const int nc = nloc >> 3, nr = nloc & 7;
            for (int ch = 0; ch < 16; ++ch) {
                const int dbase = ch * 32 + g * 8;
                short8v bf;
#pragma unroll
                for (int j = 0; j < 8; ++j) {
                    const int d = dbase + j;
                    bf[j] = (short)xbuf[d * ROWX + ((nc ^ (d & 3)) << 3) + nr];
                }
                const int csw = ((ch * 4 + g) ^ (li & 7)) << 3;
                short8v a0 = *(const short8v*)(c_lds + li * DD + csw);
                short8v a1 = *(const short8v*)(c_lds + (16 + li) * DD + csw);
                accA0 = __builtin_amdgcn_mfma_f32_16x16x32_bf16(a0, bf, accA0, 0, 0, 0);
                accA1 = __builtin_amdgcn_mfma_f32_16x16x32_bf16(a1, bf, accA1, 0, 0, 0);
            }
            // softmax over k for column nloc
            float x2v = 0.f;
#pragma unroll
            for (int p = 0; p < 8; ++p) x2v += x2_part[p * 32 + nloc];
            float sl[8];
            float mx = -3.4e38f;
#pragma unroll
            for (int r = 0; r < 4; ++r) {
                float v0 = s2_l[4 * g + r]      * (x2v - 2.f * accA0[r] + c2_l[4 * g + r]);
                float v1 = s2_l[16 + 4 * g + r] * (x2v - 2.f * accA1[r] + c2_l[16 + 4 * g + r]);
                sl[r] = v0; sl[4 + r] = v1;
                mx = fmaxf(mx, fmaxf(v0, v1));
            }
            mx = fmaxf(mx, __shfl_xor(mx, 16));
            mx = fmaxf(mx, __shfl_xor(mx, 32));
            float sum = 0.f;
#pragma unroll
            for (int i = 0; i < 8; ++i) { sl[i] = __expf(sl[i] - mx); sum += sl[i]; }
            sum += __shfl_xor(sum, 16);
            sum += __shfl_xor(sum, 32);
            const float inv = 1.f / sum;
#pragma unroll
            for (int i = 0; i < 8; ++i) {
                float a = sl[i] * inv;
                int k = (i < 4) ? (4 * g + i) : (16 + 4 * g + (i - 4));
                a_t[k * ROWA + nloc] = (u16)f2bf(a);
                float ssum = a;
                ssum += __shfl_xor(ssum, 1); ssum += __shfl_xor(ssum, 2);
                ssum += __shfl_xor(ssum, 4); ssum += __shfl_xor(ssum, 8);
                asum_acc[i] += ssum;    // valid on li==0
            }
            __builtin_amdgcn_s_setprio(0);
        }

        // ---- issue next subtile's second-half loads (staggered) ----
        if (s < SUBT - 1) {
#pragma unroll
            for (int j = 0; j < 4; ++j)
                vaB[j] = *(const float4*)(xrow + (size_t)((j + 4) * 8) * NN + (s + 1) * TNS);
        }
        SYNCL();   // 2: a_t ready (also orders x2_part(s) reads before
                   //    convert(s+1) x2_part writes)

        // ---- phase B (all 8 waves, 32x32x16): e[32 k][64 d per wave] ----
        // wave w reads ONLY its own xbuf rows [64w,64w+64) -> no barrier
        // needed between here and convert(s+1) (same-wave DS order).
        {
            const int dk = l & 31, hk = l >> 5;
            short8v af0 = *(const short8v*)(a_t + dk * ROWA + hk * 8);
            short8v af1 = *(const short8v*)(a_t + dk * ROWA + 16 + hk * 8);
            const int d0 = w * 64 + dk;
            const int d1 = d0 + 32;
            short8v x00 = *(const short8v*)(xbuf + d0 * ROWX + (((hk)     ^ (d0 & 3)) << 3));
            short8v x01 = *(const short8v*)(xbuf + d0 * ROWX + (((2 + hk) ^ (d0 & 3)) << 3));
            short8v x10 = *(const short8v*)(xbuf + d1 * ROWX + (((hk)     ^ (d1 & 3)) << 3));
            short8v x11 = *(const short8v*)(xbuf + d1 * ROWX + (((2 + hk) ^ (d1 & 3)) << 3));
            accW[0] = __builtin_amdgcn_mfma_f32_32x32x16_bf16(af0, x00, accW[0], 0, 0, 0);
            accW[1] = __builtin_amdgcn_mfma_f32_32x32x16_bf16(af0, x10, accW[1], 0, 0, 0);
            accW[0] = __builtin_amdgcn_mfma_f32_32x32x16_bf16(af1, x01, accW[0], 0, 0, 0);
            accW[1] = __builtin_amdgcn_mfma_f32_32x32x16_bf16(af1, x11, accW[1], 0, 0, 0);
        }
        // (barrier 3 removed — see layout comment block for the hazard proof)
    }

    // ---- asum -> ws ----
    if (isA && li == 0) {
#pragma unroll
        for (int i = 0; i < 8; ++i) {
            int k = (i < 4) ? (4 * g + i) : (16 + 4 * g + (i - 4));
            asum_p[wa * KK + k] = asum_acc[i];
        }
    }
    __syncthreads();
    if (t < KK) ws_asum[(size_t)blk * KK + t] = asum_p[t] + asum_p[KK + t];

    // ---- e partials -> ws (once per block); 32x32 C-layout:
    //      k = (r&3) + 8*(r>>2) + 4*hk, d = w*64 + tile*32 + (l&31)
    {
        const int dk = l & 31, hk = l >> 5;
        const size_t ebase = (size_t)blk * KK * DD;
#pragma unroll
        for (int tile = 0; tile < 2; ++tile) {
            const int d = w * 64 + tile * 32 + dk;
#pragma unroll
            for (int r = 0; r < 16; ++r) {
                int k = (r & 3) + 8 * (r >> 2) + 4 * hk;
                ws_e[ebase + (size_t)k * DD + d] = (PART)(accW[tile][r]);
            }
        }
    }
}

// ---------------- K2 v2: 65536 threads, 4 d per thread, wave-shared asum --
__global__ void k2_reduce_h(const __half* __restrict__ ws_e, const float* __restrict__ ws_asum,
                            const float* __restrict__ cw, float* __restrict__ out) {
    const int tid = blockIdx.x * blockDim.x + threadIdx.x;   // 65536
    const int dq = tid & 127;            // d = dq*4
    const int k  = (tid >> 7) & (KK - 1);
    const int b  = tid >> 12;
    const int l  = threadIdx.x & 63;

    float av = ws_asum[(size_t)(b * NGRP + (l & 31)) * KK + k];
    av += __shfl_xor(av, 1); av += __shfl_xor(av, 2);
    av += __shfl_xor(av, 4); av += __shfl_xor(av, 8);
    av += __shfl_xor(av, 16);

    const __half* base = ws_e + ((size_t)(b * NGRP) * KK + k) * DD + dq * 4;
    float s0 = 0.f, s1 = 0.f, s2 = 0.f, s3 = 0.f;
#pragma unroll
    for (int tl = 0; tl < NGRP; ++tl) {
        const __half2* p2 = (const __half2*)(base + (size_t)tl * KK * DD);
        float2 f01 = __half22float2(p2[0]);
        float2 f23 = __half22float2(p2[1]);
        s0 += f01.x; s1 += f01.y; s2 += f23.x; s3 += f23.y;
    }
    const float4 c4 = *(const float4*)(cw + k * DD + dq * 4);
    float4 o;
    o.x = s0 - av * c4.x;
    o.y = s1 - av * c4.y;
    o.z = s2 - av * c4.z;
    o.w = s3 - av * c4.w;
    *(float4*)(out + ((size_t)(b * KK + k) * DD + dq * 4)) = o;
}

__global__ void k2_reduce_f(const float* __restrict__ ws_e, const float* __restrict__ ws_asum,
                            const float* __restrict__ cw, float* __restrict__ out) {
    int tid = blockIdx.x * blockDim.x + threadIdx.x;   // 262144
    int d = tid & (DD - 1);
    int k = (tid >> 9) & (KK - 1);
    int b = tid >> 14;
    float s = 0.f, as = 0.f;
#pragma unroll
    for (int tl = 0; tl < NGRP; ++tl) {
        int blk = b * NGRP + tl;
        s += ws_e[((size_t)blk * KK + k) * DD + d];
        as += ws_asum[(size_t)blk * KK + k];
    }
    out[tid] = s - as * cw[k * DD + d];
}

extern "C" void kernel_launch(void* const* d_in, const int* in_sizes, int n_in,
                              void* d_out, int out_size, void* d_ws, size_t ws_size,
                              hipStream_t stream) {
    const float* x = (const float*)d_in[0];
    const float* cw = (const float*)d_in[1];
    const float* scale = (const float*)d_in[2];
    float* out = (float*)d_out;

    char* ws = (char*)d_ws;
    float* ws_asum = (float*)ws;                // 512*32*4 = 65536 B
    char*  e_ptr   = ws + 65536;

    const size_t need_h = 65536 + (size_t)NBLK * KK * DD * sizeof(__half);

    if (ws_size >= need_h) {
        k1_fused<__half><<<NBLK, 512, LDS_TOTAL, stream>>>(x, cw, scale, ws_asum, (__half*)e_ptr);
        k2_reduce_h<<<(BB * KK * 128) / 256, 256, 0, stream>>>((const __half*)e_ptr, ws_asum, cw, out);
    } else {
        k1_fused<float><<<NBLK, 512, LDS_TOTAL, stream>>>(x, cw, scale, ws_asum, (float*)e_ptr);
        k2_reduce_f<<<(BB * KK * DD) / 256, 256, 0, stream>>>((const float*)e_ptr, ws_asum, cw, out);
    }
}

// Round 18
// 37.332 us; speedup vs baseline: 1.0245x; 1.0245x over previous
//
#include <hip/hip_runtime.h>
#include <hip/hip_fp16.h>

#define BB 16
#define DD 512
#define NN 4096
#define KK 32
#define TNS 32          // n per subtile
#define SUBT 4          // subtiles per block (block owns 128 n)
#define NGRP 32         // n-groups (blocks) per batch
#define NBLK (BB*NGRP)  // 512 blocks
#define ROWX 40         // xbuf row stride (bf16 elems), 80 B
#define ROWA 40         // a_t row stride

// LDS byte offsets (total 77824 -> 2 blocks/CU)
#define OFF_XBUF 0              // bf16 [512][40] = 40960
#define OFF_CLDS 40960          // bf16 c swizzled [32][512] = 32768
#define OFF_AT   73728          // bf16 [32][40] = 2560
#define OFF_X2P  76288          // f32 [8][32] = 1024
#define OFF_S2   77312          // f32 [32]
#define OFF_C2   77440          // f32 [32]
#define OFF_ASUM 77568          // f32 [2][32]
#define LDS_TOTAL 77824

// xbuf layout: byte(d,n) = d*80 + (((n>>3) ^ (d&3))<<4) + (n&7)*2
// (R8 anchor layout — do NOT touch; layout excursions R9/R10/R13 regressed.)
// R15: phase B uses mfma_32x32x16 (xbuf read once/subtile).
// R16: barrier-3 removed (phase B reads only wave-own xbuf rows; same-wave
//   DS ops are in-order, so convert(s+1) by the same wave is safe).
// R17 (REVERTED): block-parity phase-A wave spread regressed 37.36->38.25.

typedef unsigned short u16;
typedef __attribute__((ext_vector_type(8))) short short8v;
typedef __attribute__((ext_vector_type(4))) float f32x4;
typedef __attribute__((ext_vector_type(16))) float f32x16;

#define SYNCL() asm volatile("s_waitcnt lgkmcnt(0)\n\ts_barrier" ::: "memory")

__device__ __forceinline__ unsigned f2bf(float f) {
    union { float f; unsigned u; } v; v.f = f;
    unsigned r = v.u + 0x7fff + ((v.u >> 16) & 1);   // RNE
    return r >> 16;
}

// ---------------- K1: fused, staggered staging, folded c-prep ------------
template <typename PART>
__global__ __launch_bounds__(512, 4)
void k1_fused(const float* __restrict__ x, const float* __restrict__ cw,
              const float* __restrict__ scale,
              float* __restrict__ ws_asum, PART* __restrict__ ws_e) {
    extern __shared__ char smem[];
    u16*   xbuf    = (u16*)(smem + OFF_XBUF);
    u16*   c_lds   = (u16*)(smem + OFF_CLDS);
    u16*   a_t     = (u16*)(smem + OFF_AT);
    float* x2_part = (float*)(smem + OFF_X2P);
    float* s2_l    = (float*)(smem + OFF_S2);
    float* c2_l    = (float*)(smem + OFF_C2);
    float* asum_p  = (float*)(smem + OFF_ASUM);

    const int t = threadIdx.x;
    const int l = t & 63, w = t >> 6;        // lane, wave (8 waves)
    const int g = l >> 4, li = l & 15;       // 16-lane group, group-lane
    const int blk = blockIdx.x;
    const int b = blk >> 5, grp = blk & 31;
    const int n0 = grp * 128;
    const float* xg = x + (size_t)b * DD * NN + n0;

    // staging geometry: wave w owns rows [64w, 64w+64)
    const int lr = l >> 3;                   // row-subgroup 0..7
    const int lc = l & 7;                    // 16B fp32 col-group (4 n)
    const int cp = lc >> 1, lo = lc & 1;     // chunk + 8B half within chunk
    const float* xrow = xg + (size_t)(w * 64 + lr) * NN + lc * 4;
    // per-thread constant swizzled write offset: row r = w*64 + 8j + lr
    const int wswz = ((cp ^ (lr & 3)) << 4) | (lo << 3);

    // ---- prologue: c-row loads first ----
    const int ck = t >> 4, cseg = t & 15;    // 16 threads per k-row
    float4 cv[8];
    {
        const float* crow = cw + ck * DD + cseg * 32;
#pragma unroll
        for (int j = 0; j < 8; ++j) cv[j] = *(const float4*)(crow + 4 * j);
    }

    // ---- issue subtile-0 x loads (two halves) ----
    float4 vaA[4], vaB[4];
#pragma unroll
    for (int j = 0; j < 4; ++j) vaA[j] = *(const float4*)(xrow + (size_t)(j * 8) * NN);
#pragma unroll
    for (int j = 0; j < 4; ++j) vaB[j] = *(const float4*)(xrow + (size_t)((j + 4) * 8) * NN);

    // ---- stage c -> c_lds (chunk-swizzled) + c2 via 16-lane reduce ----
    {
        float c2p = 0.f;
#pragma unroll
        for (int j = 0; j < 8; ++j)
            c2p += cv[j].x * cv[j].x + cv[j].y * cv[j].y
                 + cv[j].z * cv[j].z + cv[j].w * cv[j].w;
#pragma unroll
        for (int j = 0; j < 4; ++j) {
            uint4 pk;
            asm("v_cvt_pk_bf16_f32 %0, %1, %2" : "=v"(pk.x) : "v"(cv[2*j].x),   "v"(cv[2*j].y));
            asm("v_cvt_pk_bf16_f32 %0, %1, %2" : "=v"(pk.y) : "v"(cv[2*j].z),   "v"(cv[2*j].w));
            asm("v_cvt_pk_bf16_f32 %0, %1, %2" : "=v"(pk.z) : "v"(cv[2*j+1].x), "v"(cv[2*j+1].y));
            asm("v_cvt_pk_bf16_f32 %0, %1, %2" : "=v"(pk.w) : "v"(cv[2*j+1].z), "v"(cv[2*j+1].w));
            const int dch = cseg * 4 + j;                 // 16B chunk idx 0..63
            *(uint4*)(smem + OFF_CLDS + ck * 1024 + ((dch ^ (ck & 7)) << 4)) = pk;
        }
        c2p += __shfl_xor(c2p, 1); c2p += __shfl_xor(c2p, 2);
        c2p += __shfl_xor(c2p, 4); c2p += __shfl_xor(c2p, 8);
        if ((l & 15) == 0) c2_l[ck] = c2p;
        if (t < KK) { float sc = scale[t]; s2_l[t] = sc * sc; }
    }

    // phase-B accumulators: 2 tiles of 32x32 (k all 32, d = w*64 + tile*32 + (l&31))
    f32x16 accW[2];
#pragma unroll
    for (int i = 0; i < 16; ++i) { accW[0][i] = 0.f; accW[1][i] = 0.f; }
    float asum_acc[8] = {0.f, 0.f, 0.f, 0.f, 0.f, 0.f, 0.f, 0.f};

#pragma unroll
    for (int s = 0; s < SUBT; ++s) {
        // ---- convert vaA/vaB -> xbuf (swizzled b64 writes) + x2 partials ----
        {
            float p0 = 0, p1 = 0, p2 = 0, p3 = 0;
#pragma unroll
            for (int j = 0; j < 8; ++j) {
                float4 v = (j < 4) ? vaA[j] : vaB[j - 4];
                uint2 pk;
                asm("v_cvt_pk_bf16_f32 %0, %1, %2" : "=v"(pk.x) : "v"(v.x), "v"(v.y));
                asm("v_cvt_pk_bf16_f32 %0, %1, %2" : "=v"(pk.y) : "v"(v.z), "v"(v.w));
                const int r = w * 64 + j * 8 + lr;
                *(uint2*)(smem + OFF_XBUF + r * 80 + wswz) = pk;
                p0 += v.x * v.x; p1 += v.y * v.y;
                p2 += v.z * v.z; p3 += v.w * v.w;
            }
            p0 += __shfl_xor(p0, 8); p0 += __shfl_xor(p0, 16); p0 += __shfl_xor(p0, 32);
            p1 += __shfl_xor(p1, 8); p1 += __shfl_xor(p1, 16); p1 += __shfl_xor(p1, 32);
            p2 += __shfl_xor(p2, 8); p2 += __shfl_xor(p2, 16); p2 += __shfl_xor(p2, 32);
            p3 += __shfl_xor(p3, 8); p3 += __shfl_xor(p3, 16); p3 += __shfl_xor(p3, 32);
            if (lr == 0) {
                float4 p4 = {p0, p1, p2, p3};
                *(float4*)((char*)smem + OFF_X2P + w * 128 + lc * 16) = p4;
            }
        }
        SYNCL();   // 1: xbuf + x2_part visible (also gates c_lds/c2/s2 at s=0;
                   //    also orders a_t(s-1) phase-B reads before softmax(s) writes)

        // ---- issue next subtile's first-half loads (all waves, early) ----
        if (s < SUBT - 1) {
#pragma unroll
            for (int j = 0; j < 4; ++j)
                vaA[j] = *(const float4*)(xrow + (size_t)(j * 8) * NN + (s + 1) * TNS);
        }

        // ---- phase A + softmax fused (waves 0-1, boosted priority) ----
        if (w < 2) {
            __builtin_amdgcn_s_setprio(1);
            f32x4 accA0 = {0.f, 0.f, 0.f, 0.f}, accA1 = {0.f, 0.f, 0.f, 0.f};
            const int nloc = w * 16 + li;
            const int nc = nloc >> 3, nr = nloc & 7;
            for (int ch = 0; ch < 16; ++ch) {
                const int dbase = ch * 32 + g * 8;
                short8v bf;
#pragma unroll
                for (int j = 0; j < 8; ++j) {
                    const int d = dbase + j;
                    bf[j] = (short)xbuf[d * ROWX + ((nc ^ (d & 3)) << 3) + nr];
                }
                const int csw = ((ch * 4 + g) ^ (li & 7)) << 3;
                short8v a0 = *(const short8v*)(c_lds + li * DD + csw);
                short8v a1 = *(const short8v*)(c_lds + (16 + li) * DD + csw);
                accA0 = __builtin_amdgcn_mfma_f32_16x16x32_bf16(a0, bf, accA0, 0, 0, 0);
                accA1 = __builtin_amdgcn_mfma_f32_16x16x32_bf16(a1, bf, accA1, 0, 0, 0);
            }
            // softmax over k for column nloc
            float x2v = 0.f;
#pragma unroll
            for (int p = 0; p < 8; ++p) x2v += x2_part[p * 32 + nloc];
            float sl[8];
            float mx = -3.4e38f;
#pragma unroll
            for (int r = 0; r < 4; ++r) {
                float v0 = s2_l[4 * g + r]      * (x2v - 2.f * accA0[r] + c2_l[4 * g + r]);
                float v1 = s2_l[16 + 4 * g + r] * (x2v - 2.f * accA1[r] + c2_l[16 + 4 * g + r]);
                sl[r] = v0; sl[4 + r] = v1;
                mx = fmaxf(mx, fmaxf(v0, v1));
            }
            mx = fmaxf(mx, __shfl_xor(mx, 16));
            mx = fmaxf(mx, __shfl_xor(mx, 32));
            float sum = 0.f;
#pragma unroll
            for (int i = 0; i < 8; ++i) { sl[i] = __expf(sl[i] - mx); sum += sl[i]; }
            sum += __shfl_xor(sum, 16);
            sum += __shfl_xor(sum, 32);
            const float inv = 1.f / sum;
#pragma unroll
            for (int i = 0; i < 8; ++i) {
                float a = sl[i] * inv;
                int k = (i < 4) ? (4 * g + i) : (16 + 4 * g + (i - 4));
                a_t[k * ROWA + nloc] = (u16)f2bf(a);
                float ssum = a;
                ssum += __shfl_xor(ssum, 1); ssum += __shfl_xor(ssum, 2);
                ssum += __shfl_xor(ssum, 4); ssum += __shfl_xor(ssum, 8);
                asum_acc[i] += ssum;    // valid on li==0
            }
            __builtin_amdgcn_s_setprio(0);
        }

        // ---- issue next subtile's second-half loads (staggered) ----
        if (s < SUBT - 1) {
#pragma unroll
            for (int j = 0; j < 4; ++j)
                vaB[j] = *(const float4*)(xrow + (size_t)((j + 4) * 8) * NN + (s + 1) * TNS);
        }
        SYNCL();   // 2: a_t ready (also orders x2_part(s) reads before
                   //    convert(s+1) x2_part writes)

        // ---- phase B (all 8 waves, 32x32x16): e[32 k][64 d per wave] ----
        // wave w reads ONLY its own xbuf rows [64w,64w+64) -> no barrier
        // needed between here and convert(s+1) (same-wave DS order).
        {
            const int dk = l & 31, hk = l >> 5;
            short8v af0 = *(const short8v*)(a_t + dk * ROWA + hk * 8);
            short8v af1 = *(const short8v*)(a_t + dk * ROWA + 16 + hk * 8);
            const int d0 = w * 64 + dk;
            const int d1 = d0 + 32;
            short8v x00 = *(const short8v*)(xbuf + d0 * ROWX + (((hk)     ^ (d0 & 3)) << 3));
            short8v x01 = *(const short8v*)(xbuf + d0 * ROWX + (((2 + hk) ^ (d0 & 3)) << 3));
            short8v x10 = *(const short8v*)(xbuf + d1 * ROWX + (((hk)     ^ (d1 & 3)) << 3));
            short8v x11 = *(const short8v*)(xbuf + d1 * ROWX + (((2 + hk) ^ (d1 & 3)) << 3));
            accW[0] = __builtin_amdgcn_mfma_f32_32x32x16_bf16(af0, x00, accW[0], 0, 0, 0);
            accW[1] = __builtin_amdgcn_mfma_f32_32x32x16_bf16(af0, x10, accW[1], 0, 0, 0);
            accW[0] = __builtin_amdgcn_mfma_f32_32x32x16_bf16(af1, x01, accW[0], 0, 0, 0);
            accW[1] = __builtin_amdgcn_mfma_f32_32x32x16_bf16(af1, x11, accW[1], 0, 0, 0);
        }
        // (barrier 3 removed — see layout comment block for the hazard proof)
    }

    // ---- asum -> ws ----
    if (w < 2 && li == 0) {
#pragma unroll
        for (int i = 0; i < 8; ++i) {
            int k = (i < 4) ? (4 * g + i) : (16 + 4 * g + (i - 4));
            asum_p[w * KK + k] = asum_acc[i];
        }
    }
    __syncthreads();
    if (t < KK) ws_asum[(size_t)blk * KK + t] = asum_p[t] + asum_p[KK + t];

    // ---- e partials -> ws (once per block); 32x32 C-layout:
    //      k = (r&3) + 8*(r>>2) + 4*hk, d = w*64 + tile*32 + (l&31)
    {
        const int dk = l & 31, hk = l >> 5;
        const size_t ebase = (size_t)blk * KK * DD;
#pragma unroll
        for (int tile = 0; tile < 2; ++tile) {
            const int d = w * 64 + tile * 32 + dk;
#pragma unroll
            for (int r = 0; r < 16; ++r) {
                int k = (r & 3) + 8 * (r >> 2) + 4 * hk;
                ws_e[ebase + (size_t)k * DD + d] = (PART)(accW[tile][r]);
            }
        }
    }
}

// ---------------- K2 v2: 65536 threads, 4 d per thread, wave-shared asum --
__global__ void k2_reduce_h(const __half* __restrict__ ws_e, const float* __restrict__ ws_asum,
                            const float* __restrict__ cw, float* __restrict__ out) {
    const int tid = blockIdx.x * blockDim.x + threadIdx.x;   // 65536
    const int dq = tid & 127;            // d = dq*4
    const int k  = (tid >> 7) & (KK - 1);
    const int b  = tid >> 12;
    const int l  = threadIdx.x & 63;

    float av = ws_asum[(size_t)(b * NGRP + (l & 31)) * KK + k];
    av += __shfl_xor(av, 1); av += __shfl_xor(av, 2);
    av += __shfl_xor(av, 4); av += __shfl_xor(av, 8);
    av += __shfl_xor(av, 16);

    const __half* base = ws_e + ((size_t)(b * NGRP) * KK + k) * DD + dq * 4;
    float s0 = 0.f, s1 = 0.f, s2 = 0.f, s3 = 0.f;
#pragma unroll
    for (int tl = 0; tl < NGRP; ++tl) {
        const __half2* p2 = (const __half2*)(base + (size_t)tl * KK * DD);
        float2 f01 = __half22float2(p2[0]);
        float2 f23 = __half22float2(p2[1]);
        s0 += f01.x; s1 += f01.y; s2 += f23.x; s3 += f23.y;
    }
    const float4 c4 = *(const float4*)(cw + k * DD + dq * 4);
    float4 o;
    o.x = s0 - av * c4.x;
    o.y = s1 - av * c4.y;
    o.z = s2 - av * c4.z;
    o.w = s3 - av * c4.w;
    *(float4*)(out + ((size_t)(b * KK + k) * DD + dq * 4)) = o;
}

__global__ void k2_reduce_f(const float* __restrict__ ws_e, const float* __restrict__ ws_asum,
                            const float* __restrict__ cw, float* __restrict__ out) {
    int tid = blockIdx.x * blockDim.x + threadIdx.x;   // 262144
    int d = tid & (DD - 1);
    int k = (tid >> 9) & (KK - 1);
    int b = tid >> 14;
    float s = 0.f, as = 0.f;
#pragma unroll
    for (int tl = 0; tl < NGRP; ++tl) {
        int blk = b * NGRP + tl;
        s += ws_e[((size_t)blk * KK + k) * DD + d];
        as += ws_asum[(size_t)blk * KK + k];
    }
    out[tid] = s - as * cw[k * DD + d];
}

extern "C" void kernel_launch(void* const* d_in, const int* in_sizes, int n_in,
                              void* d_out, int out_size, void* d_ws, size_t ws_size,
                              hipStream_t stream) {
    const float* x = (const float*)d_in[0];
    const float* cw = (const float*)d_in[1];
    const float* scale = (const float*)d_in[2];
    float* out = (float*)d_out;

    char* ws = (char*)d_ws;
    float* ws_asum = (float*)ws;                // 512*32*4 = 65536 B
    char*  e_ptr   = ws + 65536;

    const size_t need_h = 65536 + (size_t)NBLK * KK * DD * sizeof(__half);

    if (ws_size >= need_h) {
        k1_fused<__half><<<NBLK, 512, LDS_TOTAL, stream>>>(x, cw, scale, ws_asum, (__half*)e_ptr);
        k2_reduce_h<<<(BB * KK * 128) / 256, 256, 0, stream>>>((const __half*)e_ptr, ws_asum, cw, out);
    } else {
        k1_fused<float><<<NBLK, 512, LDS_TOTAL, stream>>>(x, cw, scale, ws_asum, (float*)e_ptr);
        k2_reduce_f<<<(BB * KK * DD) / 256, 256, 0, stream>>>((const float*)e_ptr, ws_asum, cw, out);
    }
}